// Round 15
// baseline (2562.559 us; speedup 1.0000x reference)
//
#include <hip/hip_runtime.h>
#include <hip/hip_bf16.h>
#include <math.h>

// Problem constants
#define Bq   8
#define NPix 10000
#define HH   100
#define WW   100
#define Dm   256
#define NH   8
#define HD   32
#define PTS  4
#define FFd  1024
#define Lnum 6
#define Mrows (Bq * NPix)   // 80000

typedef short bf16x8 __attribute__((ext_vector_type(8)));
typedef float f32x4 __attribute__((ext_vector_type(4)));
typedef unsigned int uint2v __attribute__((ext_vector_type(2)));

__device__ __forceinline__ float bf2f(unsigned short u) {
    return __uint_as_float(((unsigned)u) << 16);
}
__device__ __forceinline__ unsigned short f2bf(float f) {
    unsigned x = __float_as_uint(f);
    return (unsigned short)((x + 0x7fffu + ((x >> 16) & 1u)) >> 16);  // RNE
}
// tanh-form GELU
__device__ __forceinline__ float gelu_t(float v) {
    float z = 1.5957691216f * (v + 0.044715f * v * v * v);
    float e = __expf(z);
    float th = 1.0f - 2.0f / (e + 1.0f);
    return 0.5f * v * (1.0f + th);
}

// ---------------------------------------------------------------------------
// Positional encoding + add: x (fp32) and xb (bf16) = src + pe
// ---------------------------------------------------------------------------
__global__ __launch_bounds__(256) void pos_add_kernel(
    const float* __restrict__ src, float* __restrict__ x, short* __restrict__ xb)
{
    int idx = blockIdx.x * 256 + threadIdx.x;
    int c = idx & (Dm - 1);
    int n = (idx >> 8) % NPix;
    int cc = c;
    float coord;
    if (c < 128) { coord = (float)(n / WW); }
    else         { coord = (float)(n % WW); cc = c - 128; }
    int j = cc >> 1;
    float f = __expf(-logf(10000.0f) * (2.0f * (float)j) / 128.0f);
    float arg = coord * f;
    float pe = (cc & 1) ? cosf(arg) : sinf(arg);
    float val = src[idx] + pe;
    x[idx] = val;
    xb[idx] = (short)f2bf(val);
}

// ---------------------------------------------------------------------------
// Weight repack: W[l][K][N] fp32 -> Wt[l][nOff + n][K] bf16 (transpose)
// ---------------------------------------------------------------------------
__global__ __launch_bounds__(256) void repack_kernel(
    const float* __restrict__ W, short* __restrict__ Wt,
    int K, int N, int outLstride, int nOff)
{
    __shared__ float t[64][65];
    int l  = blockIdx.z;
    int k0 = blockIdx.y * 64, n0 = blockIdx.x * 64;
    const float* Wl = W + (size_t)l * K * N;
    for (int i = threadIdx.x; i < 64 * 64; i += 256) {
        int kk = i >> 6, nn = i & 63;
        float val = 0.0f;
        if (k0 + kk < K && n0 + nn < N) val = Wl[(size_t)(k0 + kk) * N + (n0 + nn)];
        t[kk][nn] = val;
    }
    __syncthreads();
    for (int i = threadIdx.x; i < 64 * 64; i += 256) {
        int nn = i >> 6, kk = i & 63;
        if (n0 + nn < N && k0 + kk < K)
            Wt[(size_t)l * outLstride + (size_t)(nOff + n0 + nn) * K + (k0 + kk)]
                = (short)f2bf(t[kk][nn]);
    }
}

// combined bias: bcat[l][352] = bv(256) | boff(64) | ba(32)
__global__ void bcat_kernel(const float* __restrict__ bv,
                            const float* __restrict__ boff,
                            const float* __restrict__ ba,
                            float* __restrict__ bcat)
{
    int l = blockIdx.x, c = threadIdx.x;
    float v;
    if (c < 256)      v = bv[l * 256 + c];
    else if (c < 320) v = boff[l * 64 + (c - 256)];
    else              v = ba[l * 32 + (c - 320)];
    bcat[l * 352 + c] = v;
}

// ---------------------------------------------------------------------------
// bf16 MFMA GEMM, 128x128 tile, 4 waves, BK=64, K = KI*64 (unrolled).
// B (weights) staged via LDS; A (activations) read DIRECT global->VGPR
// (wave-private / 2-way-shared rows -> no LDS reuse benefit). LDS 16 KB.
// Swapped operands; row-outer/col-inner merged-write epilogue.
// MODE 0: C = bf16(gelu_t(acc+bias)), ldc given (W1 path).
// MODE 2: split: cols <256 -> Cv bf16 (ld 256); cols 256.. -> C2 fp32 (ld 96).
// ---------------------------------------------------------------------------
template<int KI, int MODE>
__global__ __launch_bounds__(256) void gemm_mfma_kernel(
    const short* __restrict__ A, const short* __restrict__ Bt,
    const float* __restrict__ bias, short* __restrict__ Cv,
    float* __restrict__ C2,
    int M, int Nc, int ldc)
{
    constexpr int K = KI * 64;
    __shared__ short Bs[128 * 64];   // 16 KB
    const int tid = threadIdx.x;

    int nwg  = gridDim.x * gridDim.y;
    int orig = blockIdx.y * gridDim.x + blockIdx.x;
    int xcd  = orig & 7, pos = orig >> 3;
    int q = nwg >> 3, r = nwg & 7;
    int flat = (xcd < r ? xcd * (q + 1) : r * (q + 1) + (xcd - r) * q) + pos;
    const int bm = (flat / gridDim.x) * 128;
    const int bn = (flat % gridDim.x) * 128;

    const int w = tid >> 6, l = tid & 63;
    const int wr = (w >> 1) * 64, wc = (w & 1) * 64;
    const int rl = tid >> 3;      // 0..31
    const int cl = tid & 7;       // chunk 0..7
    const int lr = l & 15, lq = l >> 4;

    // B staging pointers (hoisted)
    const short* pB[4];
    #pragma unroll
    for (int p = 0; p < 4; ++p) {
        int row = p * 32 + rl;
        int sc  = cl ^ (row & 7);
        int gb  = bn + row; if (gb > Nc - 1) gb = Nc - 1;
        pB[p] = Bt + (size_t)gb * K + sc * 8;
    }

    // direct A pointers (one per row-group), pre-offset by lq*8 shorts
    const short* pAg[4];
    #pragma unroll
    for (int n = 0; n < 4; ++n) {
        int ra = bm + wr + n * 16 + lr;
        if (ra > M - 1) ra = M - 1;
        pAg[n] = A + (size_t)ra * K + lq * 8;
    }

    int woff[2][4];
    #pragma unroll
    for (int ks = 0; ks < 2; ++ks)
        #pragma unroll
        for (int m = 0; m < 4; ++m) {
            int rb = wc + m * 16 + lr;
            woff[ks][m] = rb * 64 + (((ks * 4 + lq) ^ (rb & 7))) * 8;
        }

    f32x4 acc[4][4];   // [m = out-col group][n = out-row group]
    #pragma unroll
    for (int m = 0; m < 4; ++m)
        #pragma unroll
        for (int n = 0; n < 4; ++n)
            #pragma unroll
            for (int j = 0; j < 4; ++j) acc[m][n][j] = 0.0f;

    #pragma unroll
    for (int kc = 0; kc < KI; ++kc) {
        #pragma unroll
        for (int p = 0; p < 4; ++p) {
            __builtin_amdgcn_global_load_lds((const void*)pB[p],
                (void*)&Bs[(p * 32 + w * 8) * 64], 16, 0, 0);
            pB[p] += 64;
        }
        __syncthreads();

        #pragma unroll
        for (int ks = 0; ks < 2; ++ks) {
            bf16x8 wf[4], xf[4];
            #pragma unroll
            for (int n = 0; n < 4; ++n)
                xf[n] = *(const bf16x8*)(pAg[n] + kc * 64 + ks * 32);
            #pragma unroll
            for (int m = 0; m < 4; ++m) wf[m] = *(const bf16x8*)&Bs[woff[ks][m]];
            #pragma unroll
            for (int m = 0; m < 4; ++m)
                #pragma unroll
                for (int n = 0; n < 4; ++n)
                    acc[m][n] = __builtin_amdgcn_mfma_f32_16x16x32_bf16(
                        wf[m], xf[n], acc[m][n], 0, 0, 0);
        }
        __syncthreads();
    }

    float4 bi[4];
    #pragma unroll
    for (int m = 0; m < 4; ++m) {
        int colBase = bn + wc + m * 16 + lq * 4;
        bi[m] = (MODE == 2 && colBase >= Nc) ? float4{0,0,0,0}
                                             : *(const float4*)&bias[colBase];
    }

    #pragma unroll
    for (int n = 0; n < 4; ++n) {
        int rr = bm + wr + n * 16 + lr;
        if (rr >= M) continue;
        #pragma unroll
        for (int m = 0; m < 4; ++m) {
            int colBase = bn + wc + m * 16 + lq * 4;
            if (MODE == 2 && colBase >= Nc) continue;
            float o0 = acc[m][n][0] + bi[m].x;
            float o1 = acc[m][n][1] + bi[m].y;
            float o2 = acc[m][n][2] + bi[m].z;
            float o3 = acc[m][n][3] + bi[m].w;
            if (MODE == 0) {
                o0 = gelu_t(o0); o1 = gelu_t(o1); o2 = gelu_t(o2); o3 = gelu_t(o3);
                uint2v pk;
                pk.x = (unsigned)f2bf(o0) | ((unsigned)f2bf(o1) << 16);
                pk.y = (unsigned)f2bf(o2) | ((unsigned)f2bf(o3) << 16);
                *(uint2v*)&Cv[(size_t)rr * ldc + colBase] = pk;
            } else {
                if (colBase < 256) {
                    uint2v pk;
                    pk.x = (unsigned)f2bf(o0) | ((unsigned)f2bf(o1) << 16);
                    pk.y = (unsigned)f2bf(o2) | ((unsigned)f2bf(o3) << 16);
                    *(uint2v*)&Cv[(size_t)rr * 256 + colBase] = pk;
                } else {
                    float4 pk; pk.x = o0; pk.y = o1; pk.z = o2; pk.w = o3;
                    *(float4*)&C2[(size_t)rr * 96 + (colBase - 256)] = pk;
                }
            }
        }
    }
}

// ---------------------------------------------------------------------------
// bf16 MFMA GEMM + fused residual+LayerNorm epilogue. K = KI*64 (unrolled).
// BM=128, BN=256, 8 waves (512 threads). B staged via LDS (32 KB); A rows are
// WAVE-PRIVATE -> read direct global->VGPR (no As LDS, no A-barrier dep).
// LDS 32 KB -> 4 blocks/CU (wave cap) vs 3.
// ---------------------------------------------------------------------------
template<int KI>
__global__ __launch_bounds__(512) void gemm_ln_kernel(
    const short* __restrict__ A, const short* __restrict__ Bt,
    const float* __restrict__ bias,
    const float* __restrict__ gw, const float* __restrict__ bw,
    float* __restrict__ x, short* __restrict__ xb,
    int M)
{
    constexpr int K = KI * 64;
    __shared__ short Bs[256 * 64];   // 32 KB
    const int tid = threadIdx.x;     // 0..511
    const int bm = blockIdx.x * 128;
    const int w = tid >> 6, l = tid & 63;
    const int lr = l & 15, lq = l >> 4;

    // B staging pointers: 2048 chunks, 4/thread
    const short* pB[4];
    #pragma unroll
    for (int p = 0; p < 4; ++p) {
        int s = p * 512 + tid;
        int row = s >> 3, cs = s & 7;
        int sc  = cs ^ (row & 7);
        pB[p] = Bt + (size_t)row * K + sc * 8;
    }

    // direct A pointer: wave-private row, pre-offset by lq*8
    const int arow = w * 16 + lr;    // 0..127
    int raC = bm + arow; if (raC > M - 1) raC = M - 1;
    const short* pAg = A + (size_t)raC * K + lq * 8;

    int boff[2][16];
    #pragma unroll
    for (int ks = 0; ks < 2; ++ks)
        #pragma unroll
        for (int i = 0; i < 16; ++i) {
            int brow = i * 16 + lr;
            boff[ks][i] = brow * 64 + (((ks * 4 + lq) ^ (brow & 7))) * 8;
        }

    f32x4 acc[16];
    #pragma unroll
    for (int n = 0; n < 16; ++n)
        #pragma unroll
        for (int j = 0; j < 4; ++j) acc[n][j] = 0.0f;

    #pragma unroll
    for (int kc = 0; kc < KI; ++kc) {
        #pragma unroll
        for (int p = 0; p < 4; ++p) {
            __builtin_amdgcn_global_load_lds((const void*)pB[p],
                (void*)&Bs[(p * 512 + w * 64) * 8], 16, 0, 0);
            pB[p] += 64;
        }
        __syncthreads();

        #pragma unroll
        for (int ks = 0; ks < 2; ++ks) {
            bf16x8 af = *(const bf16x8*)(pAg + kc * 64 + ks * 32);
            #pragma unroll
            for (int hb = 0; hb < 2; ++hb) {
                bf16x8 bfr[8];
                #pragma unroll
                for (int i = 0; i < 8; ++i)
                    bfr[i] = *(const bf16x8*)&Bs[boff[ks][hb * 8 + i]];
                #pragma unroll
                for (int i = 0; i < 8; ++i)
                    acc[hb * 8 + i] = __builtin_amdgcn_mfma_f32_16x16x32_bf16(
                        af, bfr[i], acc[hb * 8 + i], 0, 0, 0);
            }
        }
        __syncthreads();
    }

    float bi[16];
    #pragma unroll
    for (int n = 0; n < 16; ++n) bi[n] = bias[n * 16 + lr];

    #pragma unroll
    for (int j = 0; j < 4; ++j) {
        int rr = bm + w * 16 + lq * 4 + j;
        if (rr < M) {
            float tmp[16];
            float sum = 0.0f;
            #pragma unroll
            for (int n = 0; n < 16; ++n) {
                int c = n * 16 + lr;
                float val = acc[n][j] + bi[n] + x[(size_t)rr * 256 + c];
                tmp[n] = val;
                sum += val;
            }
            #pragma unroll
            for (int o = 8; o >= 1; o >>= 1) sum += __shfl_xor(sum, o);
            float mean = sum * (1.0f / 256.0f);
            float vs = 0.0f;
            #pragma unroll
            for (int n = 0; n < 16; ++n) {
                float d = tmp[n] - mean;
                vs += d * d;
            }
            #pragma unroll
            for (int o = 8; o >= 1; o >>= 1) vs += __shfl_xor(vs, o);
            float rstd = rsqrtf(vs * (1.0f / 256.0f) + 1e-5f);
            #pragma unroll
            for (int n = 0; n < 16; ++n) {
                int c = n * 16 + lr;
                float ov = (tmp[n] - mean) * rstd * gw[c] + bw[c];
                x[(size_t)rr * 256 + c] = ov;
                xb[(size_t)rr * 256 + c] = (short)f2bf(ov);
            }
        }
    }
}

// ---------------------------------------------------------------------------
// Deformable sampling. v bf16 [CM,256], comb fp32 [CM,96], out bf16 [CM,256].
// ---------------------------------------------------------------------------
__global__ __launch_bounds__(256) void deform_attn_kernel(
    const short* __restrict__ v, const float* __restrict__ comb,
    short* __restrict__ outs)
{
    int g  = blockIdx.x * 16 + (threadIdx.x >> 4);
    int d2 = threadIdx.x & 15;
    int bn = g >> 3, h = g & 7;
    int n  = bn % NPix;
    int row = n / WW, col = n % WW;
    int base_v = (bn / NPix) * NPix;

    const float* cb = comb + (size_t)bn * 96;
    float l0 = cb[64 + h * 4 + 0], l1 = cb[64 + h * 4 + 1];
    float l2 = cb[64 + h * 4 + 2], l3 = cb[64 + h * 4 + 3];
    float mx = fmaxf(fmaxf(l0, l1), fmaxf(l2, l3));
    float e0 = __expf(l0 - mx), e1 = __expf(l1 - mx);
    float e2 = __expf(l2 - mx), e3 = __expf(l3 - mx);
    float inv = 1.0f / (e0 + e1 + e2 + e3);
    float aw[4] = {e0 * inv, e1 * inv, e2 * inv, e3 * inv};

    float acc0 = 0.0f, acc1 = 0.0f;
    size_t chb = (size_t)h * HD + d2 * 2;
    #pragma unroll
    for (int p = 0; p < 4; ++p) {
        float dx = cb[h * 8 + p * 2 + 0];
        float dy = cb[h * 8 + p * 2 + 1];
        float px = (float)col + dx;
        float py = (float)row + dy;
        float x0f = floorf(px), y0f = floorf(py);
        float wx = px - x0f, wy = py - y0f;
        int x0i = min(max((int)x0f, 0), WW - 1);
        int y0i = min(max((int)y0f, 0), HH - 1);
        int x1i = min(x0i + 1, WW - 1);
        int y1i = min(y0i + 1, HH - 1);
        unsigned u00 = *(const unsigned*)&v[(size_t)(base_v + y0i * WW + x0i) * Dm + chb];
        unsigned u01 = *(const unsigned*)&v[(size_t)(base_v + y0i * WW + x1i) * Dm + chb];
        unsigned u10 = *(const unsigned*)&v[(size_t)(base_v + y1i * WW + x0i) * Dm + chb];
        unsigned u11 = *(const unsigned*)&v[(size_t)(base_v + y1i * WW + x1i) * Dm + chb];
        float w00 = (1.0f - wx) * (1.0f - wy), w01 = wx * (1.0f - wy);
        float w10 = (1.0f - wx) * wy,          w11 = wx * wy;
        float s0 = bf2f((unsigned short)u00) * w00 + bf2f((unsigned short)u01) * w01
                 + bf2f((unsigned short)u10) * w10 + bf2f((unsigned short)u11) * w11;
        float s1 = bf2f((unsigned short)(u00 >> 16)) * w00 + bf2f((unsigned short)(u01 >> 16)) * w01
                 + bf2f((unsigned short)(u10 >> 16)) * w10 + bf2f((unsigned short)(u11 >> 16)) * w11;
        acc0 = fmaf(aw[p], s0, acc0);
        acc1 = fmaf(aw[p], s1, acc1);
    }
    unsigned outw = (unsigned)f2bf(acc0) | ((unsigned)f2bf(acc1) << 16);
    *(unsigned*)&outs[(size_t)bn * Dm + chb] = outw;
}

// ---------------------------------------------------------------------------
extern "C" void kernel_launch(void* const* d_in, const int* in_sizes, int n_in,
                              void* d_out, int out_size, void* d_ws, size_t ws_size,
                              hipStream_t stream)
{
    const float* src  = (const float*)d_in[0];
    const float* Wv   = (const float*)d_in[1];
    const float* bv   = (const float*)d_in[2];
    const float* Woff = (const float*)d_in[3];
    const float* boff = (const float*)d_in[4];
    const float* Wa   = (const float*)d_in[5];
    const float* ba   = (const float*)d_in[6];
    const float* Wo   = (const float*)d_in[7];
    const float* bo   = (const float*)d_in[8];
    const float* W1   = (const float*)d_in[9];
    const float* b1   = (const float*)d_in[10];
    const float* W2   = (const float*)d_in[11];
    const float* b2   = (const float*)d_in[12];
    const float* g1   = (const float*)d_in[13];
    const float* be1  = (const float*)d_in[14];
    const float* g2   = (const float*)d_in[15];
    const float* be2  = (const float*)d_in[16];

    float* x = (float*)d_out;   // fp32 master activations

    char* cur = (char*)d_ws;
    auto take = [&](size_t bytes) { char* p = cur; cur += (bytes + 255) & ~(size_t)255; return p; };
    short* WcatT = (short*)take((size_t)Lnum * 352 * Dm * 2);
    short* WoT   = (short*)take((size_t)Lnum * Dm * Dm * 2);
    short* W1T   = (short*)take((size_t)Lnum * Dm * FFd * 2);  // [l][1024][256]
    short* W2T   = (short*)take((size_t)Lnum * FFd * Dm * 2);  // [l][256][1024]
    float* bcat  = (float*)take((size_t)Lnum * 352 * 4);
    short* xb    = (short*)take((size_t)Mrows * Dm * 2);
    size_t fixedB = (size_t)(cur - (char*)d_ws);

    const size_t perRowB = 512 + 512 + 384 + 2048;   // v, sbuf, comb, h
    int k = 8;
    while (k > 1 && fixedB + (size_t)k * NPix * perRowB > ws_size) k >>= 1;
    if (fixedB + (size_t)k * NPix * perRowB > ws_size) return;
    const int CM = k * NPix;
    const int nChunks = Bq / k;

    short* v    = (short*)take((size_t)CM * Dm * 2);
    short* sbuf = (short*)take((size_t)CM * Dm * 2);
    float* comb = (float*)take((size_t)CM * 96 * 4);
    short* h    = (short*)take((size_t)CM * FFd * 2);

    repack_kernel<<<dim3(4, 4, Lnum),  256, 0, stream>>>(Wv,   WcatT, Dm,  Dm,  352 * Dm,   0);
    repack_kernel<<<dim3(1, 4, Lnum),  256, 0, stream>>>(Woff, WcatT, Dm,  64,  352 * Dm, 256);
    repack_kernel<<<dim3(1, 4, Lnum),  256, 0, stream>>>(Wa,   WcatT, Dm,  32,  352 * Dm, 320);
    repack_kernel<<<dim3(4, 4, Lnum),  256, 0, stream>>>(Wo,   WoT,   Dm,  Dm,  Dm * Dm,    0);
    repack_kernel<<<dim3(16, 4, Lnum), 256, 0, stream>>>(W1,   W1T,   Dm,  FFd, Dm * FFd,   0);
    repack_kernel<<<dim3(4, 16, Lnum), 256, 0, stream>>>(W2,   W2T,   FFd, Dm,  FFd * Dm,   0);
    bcat_kernel<<<Lnum, 352, 0, stream>>>(bv, boff, ba, bcat);

    pos_add_kernel<<<Mrows, 256, 0, stream>>>(src, x, xb);

    const int gy128 = (CM + 127) / 128;   // 625
    const int gLN   = (CM + 127) / 128;

    for (int l = 0; l < Lnum; ++l) {
        const short* WcatT_l = WcatT + (size_t)l * 352 * Dm;
        const short* WoT_l   = WoT   + (size_t)l * Dm * Dm;
        const short* W1T_l   = W1T   + (size_t)l * Dm * FFd;
        const short* W2T_l   = W2T   + (size_t)l * FFd * Dm;

        for (int c = 0; c < nChunks; ++c) {
            size_t rowOff = (size_t)c * CM;
            float* xc  = x  + rowOff * Dm;
            short* xbc = xb + rowOff * Dm;

            // v | comb = xb @ WcatT  (K=256)
            gemm_mfma_kernel<4, 2><<<dim3(3, gy128), 256, 0, stream>>>(
                xbc, WcatT_l, bcat + l * 352, v, comb, CM, 352, 0);
            // sbuf = deformable sampling (bf16)
            deform_attn_kernel<<<CM / 2, 256, 0, stream>>>(v, comb, sbuf);
            // x = LN(x + sbuf @ WoT + bo)  (K=256)
            gemm_ln_kernel<4><<<gLN, 512, 0, stream>>>(
                sbuf, WoT_l, bo + l * Dm, g1 + l * Dm, be1 + l * Dm, xc, xbc, CM);
            // h = gelu(xb @ W1T + b1)  (K=256, Nc=1024)
            gemm_mfma_kernel<4, 0><<<dim3(8, gy128), 256, 0, stream>>>(
                xbc, W1T_l, b1 + l * FFd, h, nullptr, CM, FFd, FFd);
            // x = LN(x + h @ W2T + b2)  (K=1024)
            gemm_ln_kernel<16><<<gLN, 512, 0, stream>>>(
                h, W2T_l, b2 + l * Dm, g2 + l * Dm, be2 + l * Dm, xc, xbc, CM);
        }
    }
}

// Round 16
// 2178.977 us; speedup vs baseline: 1.1760x; 1.1760x over previous
//
#include <hip/hip_runtime.h>
#include <hip/hip_bf16.h>
#include <math.h>

// Problem constants
#define Bq   8
#define NPix 10000
#define HH   100
#define WW   100
#define Dm   256
#define NH   8
#define HD   32
#define PTS  4
#define FFd  1024
#define Lnum 6
#define Mrows (Bq * NPix)   // 80000

typedef short bf16x8 __attribute__((ext_vector_type(8)));
typedef float f32x4 __attribute__((ext_vector_type(4)));
typedef unsigned int uint2v __attribute__((ext_vector_type(2)));

__device__ __forceinline__ float bf2f(unsigned short u) {
    return __uint_as_float(((unsigned)u) << 16);
}
__device__ __forceinline__ unsigned short f2bf(float f) {
    unsigned x = __float_as_uint(f);
    return (unsigned short)((x + 0x7fffu + ((x >> 16) & 1u)) >> 16);  // RNE
}
// tanh-form GELU; fast rcp for the sigmoid-style divide
__device__ __forceinline__ float gelu_t(float v) {
    float z = 1.5957691216f * (v + 0.044715f * v * v * v);
    float e = __expf(z);
    float th = 1.0f - 2.0f * __builtin_amdgcn_rcpf(e + 1.0f);
    return 0.5f * v * (1.0f + th);
}

// ---------------------------------------------------------------------------
// Positional encoding + add: x (fp32) and xb (bf16) = src + pe
// ---------------------------------------------------------------------------
__global__ __launch_bounds__(256) void pos_add_kernel(
    const float* __restrict__ src, float* __restrict__ x, short* __restrict__ xb)
{
    int idx = blockIdx.x * 256 + threadIdx.x;
    int c = idx & (Dm - 1);
    int n = (idx >> 8) % NPix;
    int cc = c;
    float coord;
    if (c < 128) { coord = (float)(n / WW); }
    else         { coord = (float)(n % WW); cc = c - 128; }
    int j = cc >> 1;
    float f = __expf(-logf(10000.0f) * (2.0f * (float)j) / 128.0f);
    float arg = coord * f;
    float pe = (cc & 1) ? cosf(arg) : sinf(arg);
    float val = src[idx] + pe;
    x[idx] = val;
    xb[idx] = (short)f2bf(val);
}

// ---------------------------------------------------------------------------
// Weight repack: W[l][K][N] fp32 -> Wt[l][nOff + n][K] bf16 (transpose)
// ---------------------------------------------------------------------------
__global__ __launch_bounds__(256) void repack_kernel(
    const float* __restrict__ W, short* __restrict__ Wt,
    int K, int N, int outLstride, int nOff)
{
    __shared__ float t[64][65];
    int l  = blockIdx.z;
    int k0 = blockIdx.y * 64, n0 = blockIdx.x * 64;
    const float* Wl = W + (size_t)l * K * N;
    for (int i = threadIdx.x; i < 64 * 64; i += 256) {
        int kk = i >> 6, nn = i & 63;
        float val = 0.0f;
        if (k0 + kk < K && n0 + nn < N) val = Wl[(size_t)(k0 + kk) * N + (n0 + nn)];
        t[kk][nn] = val;
    }
    __syncthreads();
    for (int i = threadIdx.x; i < 64 * 64; i += 256) {
        int nn = i >> 6, kk = i & 63;
        if (n0 + nn < N && k0 + kk < K)
            Wt[(size_t)l * outLstride + (size_t)(nOff + n0 + nn) * K + (k0 + kk)]
                = (short)f2bf(t[kk][nn]);
    }
}

// combined bias: bcat[l][352] = bv(256) | boff(64) | ba(32)
__global__ void bcat_kernel(const float* __restrict__ bv,
                            const float* __restrict__ boff,
                            const float* __restrict__ ba,
                            float* __restrict__ bcat)
{
    int l = blockIdx.x, c = threadIdx.x;
    float v;
    if (c < 256)      v = bv[l * 256 + c];
    else if (c < 320) v = boff[l * 64 + (c - 256)];
    else              v = ba[l * 32 + (c - 320)];
    bcat[l * 352 + c] = v;
}

// ---------------------------------------------------------------------------
// bf16 MFMA GEMM, 128x128 tile, 4 waves, BK=64, K = KI*64 (unrolled),
// single-buffered. Swapped operands; row-outer/col-inner merged-write epilogue.
// MODE 0: C = bf16(gelu_t(acc+bias)), ldc given (W1 path).
// MODE 2: split: cols <256 -> Cv bf16 (ld 256); cols 256.. -> C2 fp32 (ld 96).
// ---------------------------------------------------------------------------
template<int KI, int MODE>
__global__ __launch_bounds__(256) void gemm_mfma_kernel(
    const short* __restrict__ A, const short* __restrict__ Bt,
    const float* __restrict__ bias, short* __restrict__ Cv,
    float* __restrict__ C2,
    int M, int Nc, int ldc)
{
    constexpr int K = KI * 64;
    __shared__ short As[128 * 64];
    __shared__ short Bs[128 * 64];
    const int tid = threadIdx.x;

    int nwg  = gridDim.x * gridDim.y;
    int orig = blockIdx.y * gridDim.x + blockIdx.x;
    int xcd  = orig & 7, pos = orig >> 3;
    int q = nwg >> 3, r = nwg & 7;
    int flat = (xcd < r ? xcd * (q + 1) : r * (q + 1) + (xcd - r) * q) + pos;
    const int bm = (flat / gridDim.x) * 128;
    const int bn = (flat % gridDim.x) * 128;

    const int w = tid >> 6, l = tid & 63;
    const int wr = (w >> 1) * 64, wc = (w & 1) * 64;
    const int rl = tid >> 3;      // 0..31
    const int cl = tid & 7;       // chunk 0..7
    const int lr = l & 15, lq = l >> 4;

    const short* pA[4]; const short* pB[4];
    #pragma unroll
    for (int p = 0; p < 4; ++p) {
        int row = p * 32 + rl;
        int sc  = cl ^ (row & 7);
        int ga  = bm + row; if (ga > M - 1) ga = M - 1;
        pA[p] = A + (size_t)ga * K + sc * 8;
        int gb  = bn + row; if (gb > Nc - 1) gb = Nc - 1;
        pB[p] = Bt + (size_t)gb * K + sc * 8;
    }

    int xoff[2][4], woff[2][4];
    #pragma unroll
    for (int ks = 0; ks < 2; ++ks)
        #pragma unroll
        for (int m = 0; m < 4; ++m) {
            int ra = wr + m * 16 + lr;
            xoff[ks][m] = ra * 64 + (((ks * 4 + lq) ^ (ra & 7))) * 8;
            int rb = wc + m * 16 + lr;
            woff[ks][m] = rb * 64 + (((ks * 4 + lq) ^ (rb & 7))) * 8;
        }

    f32x4 acc[4][4];   // [m = out-col group][n = out-row group]
    #pragma unroll
    for (int m = 0; m < 4; ++m)
        #pragma unroll
        for (int n = 0; n < 4; ++n)
            #pragma unroll
            for (int j = 0; j < 4; ++j) acc[m][n][j] = 0.0f;

    #pragma unroll
    for (int kc = 0; kc < KI; ++kc) {
        #pragma unroll
        for (int p = 0; p < 4; ++p) {
            __builtin_amdgcn_global_load_lds((const void*)pA[p],
                (void*)&As[(p * 32 + w * 8) * 64], 16, 0, 0);
            pA[p] += 64;
            __builtin_amdgcn_global_load_lds((const void*)pB[p],
                (void*)&Bs[(p * 32 + w * 8) * 64], 16, 0, 0);
            pB[p] += 64;
        }
        __syncthreads();

        #pragma unroll
        for (int ks = 0; ks < 2; ++ks) {
            bf16x8 wf[4], xf[4];
            #pragma unroll
            for (int m = 0; m < 4; ++m) wf[m] = *(const bf16x8*)&Bs[woff[ks][m]];
            #pragma unroll
            for (int n = 0; n < 4; ++n) xf[n] = *(const bf16x8*)&As[xoff[ks][n]];
            #pragma unroll
            for (int m = 0; m < 4; ++m)
                #pragma unroll
                for (int n = 0; n < 4; ++n)
                    acc[m][n] = __builtin_amdgcn_mfma_f32_16x16x32_bf16(
                        wf[m], xf[n], acc[m][n], 0, 0, 0);
        }
        __syncthreads();
    }

    float4 bi[4];
    #pragma unroll
    for (int m = 0; m < 4; ++m) {
        int colBase = bn + wc + m * 16 + lq * 4;
        bi[m] = (MODE == 2 && colBase >= Nc) ? float4{0,0,0,0}
                                             : *(const float4*)&bias[colBase];
    }

    #pragma unroll
    for (int n = 0; n < 4; ++n) {
        int rr = bm + wr + n * 16 + lr;
        if (rr >= M) continue;
        #pragma unroll
        for (int m = 0; m < 4; ++m) {
            int colBase = bn + wc + m * 16 + lq * 4;
            if (MODE == 2 && colBase >= Nc) continue;
            float o0 = acc[m][n][0] + bi[m].x;
            float o1 = acc[m][n][1] + bi[m].y;
            float o2 = acc[m][n][2] + bi[m].z;
            float o3 = acc[m][n][3] + bi[m].w;
            if (MODE == 0) {
                o0 = gelu_t(o0); o1 = gelu_t(o1); o2 = gelu_t(o2); o3 = gelu_t(o3);
                uint2v pk;
                pk.x = (unsigned)f2bf(o0) | ((unsigned)f2bf(o1) << 16);
                pk.y = (unsigned)f2bf(o2) | ((unsigned)f2bf(o3) << 16);
                *(uint2v*)&Cv[(size_t)rr * ldc + colBase] = pk;
            } else {
                if (colBase < 256) {
                    uint2v pk;
                    pk.x = (unsigned)f2bf(o0) | ((unsigned)f2bf(o1) << 16);
                    pk.y = (unsigned)f2bf(o2) | ((unsigned)f2bf(o3) << 16);
                    *(uint2v*)&Cv[(size_t)rr * 256 + colBase] = pk;
                } else {
                    float4 pk; pk.x = o0; pk.y = o1; pk.z = o2; pk.w = o3;
                    *(float4*)&C2[(size_t)rr * 96 + (colBase - 256)] = pk;
                }
            }
        }
    }
}

// ---------------------------------------------------------------------------
// bf16 MFMA GEMM + fused residual+LayerNorm epilogue. K = KI*64 (unrolled).
// BM=128, BN=256, 8 waves (512 threads).  (R13 proven version.)
// ---------------------------------------------------------------------------
template<int KI>
__global__ __launch_bounds__(512) void gemm_ln_kernel(
    const short* __restrict__ A, const short* __restrict__ Bt,
    const float* __restrict__ bias,
    const float* __restrict__ gw, const float* __restrict__ bw,
    float* __restrict__ x, short* __restrict__ xb,
    int M)
{
    constexpr int K = KI * 64;
    __shared__ short As[128 * 64];   // 16 KB
    __shared__ short Bs[256 * 64];   // 32 KB
    const int tid = threadIdx.x;     // 0..511
    const int bm = blockIdx.x * 128;
    const int w = tid >> 6, l = tid & 63;
    const int lr = l & 15, lq = l >> 4;

    const short* pA[2]; const short* pB[4];
    #pragma unroll
    for (int p = 0; p < 2; ++p) {
        int s = p * 512 + tid;
        int row = s >> 3, cs = s & 7;
        int sc  = cs ^ (row & 7);
        int ga  = bm + row; if (ga > M - 1) ga = M - 1;
        pA[p] = A + (size_t)ga * K + sc * 8;
    }
    #pragma unroll
    for (int p = 0; p < 4; ++p) {
        int s = p * 512 + tid;
        int row = s >> 3, cs = s & 7;
        int sc  = cs ^ (row & 7);
        pB[p] = Bt + (size_t)row * K + sc * 8;
    }

    const int arow = w * 16 + lr;    // 0..127
    int aoff[2];
    #pragma unroll
    for (int ks = 0; ks < 2; ++ks)
        aoff[ks] = arow * 64 + (((ks * 4 + lq) ^ (arow & 7))) * 8;
    int boff[2][16];
    #pragma unroll
    for (int ks = 0; ks < 2; ++ks)
        #pragma unroll
        for (int i = 0; i < 16; ++i) {
            int brow = i * 16 + lr;
            boff[ks][i] = brow * 64 + (((ks * 4 + lq) ^ (brow & 7))) * 8;
        }

    f32x4 acc[16];
    #pragma unroll
    for (int n = 0; n < 16; ++n)
        #pragma unroll
        for (int j = 0; j < 4; ++j) acc[n][j] = 0.0f;

    #pragma unroll
    for (int kc = 0; kc < KI; ++kc) {
        #pragma unroll
        for (int p = 0; p < 2; ++p) {
            __builtin_amdgcn_global_load_lds((const void*)pA[p],
                (void*)&As[(p * 512 + w * 64) * 8], 16, 0, 0);
            pA[p] += 64;
        }
        #pragma unroll
        for (int p = 0; p < 4; ++p) {
            __builtin_amdgcn_global_load_lds((const void*)pB[p],
                (void*)&Bs[(p * 512 + w * 64) * 8], 16, 0, 0);
            pB[p] += 64;
        }
        __syncthreads();

        #pragma unroll
        for (int ks = 0; ks < 2; ++ks) {
            bf16x8 af = *(const bf16x8*)&As[aoff[ks]];
            #pragma unroll
            for (int hb = 0; hb < 2; ++hb) {
                bf16x8 bfr[8];
                #pragma unroll
                for (int i = 0; i < 8; ++i)
                    bfr[i] = *(const bf16x8*)&Bs[boff[ks][hb * 8 + i]];
                #pragma unroll
                for (int i = 0; i < 8; ++i)
                    acc[hb * 8 + i] = __builtin_amdgcn_mfma_f32_16x16x32_bf16(
                        af, bfr[i], acc[hb * 8 + i], 0, 0, 0);
            }
        }
        __syncthreads();
    }

    float bi[16];
    #pragma unroll
    for (int n = 0; n < 16; ++n) bi[n] = bias[n * 16 + lr];

    #pragma unroll
    for (int j = 0; j < 4; ++j) {
        int rr = bm + w * 16 + lq * 4 + j;
        if (rr < M) {
            float tmp[16];
            float sum = 0.0f;
            #pragma unroll
            for (int n = 0; n < 16; ++n) {
                int c = n * 16 + lr;
                float val = acc[n][j] + bi[n] + x[(size_t)rr * 256 + c];
                tmp[n] = val;
                sum += val;
            }
            #pragma unroll
            for (int o = 8; o >= 1; o >>= 1) sum += __shfl_xor(sum, o);
            float mean = sum * (1.0f / 256.0f);
            float vs = 0.0f;
            #pragma unroll
            for (int n = 0; n < 16; ++n) {
                float d = tmp[n] - mean;
                vs += d * d;
            }
            #pragma unroll
            for (int o = 8; o >= 1; o >>= 1) vs += __shfl_xor(vs, o);
            float rstd = rsqrtf(vs * (1.0f / 256.0f) + 1e-5f);
            #pragma unroll
            for (int n = 0; n < 16; ++n) {
                int c = n * 16 + lr;
                float ov = (tmp[n] - mean) * rstd * gw[c] + bw[c];
                x[(size_t)rr * 256 + c] = ov;
                xb[(size_t)rr * 256 + c] = (short)f2bf(ov);
            }
        }
    }
}

// ---------------------------------------------------------------------------
// Deformable sampling. v bf16 [CM,256], comb fp32 [CM,96], out bf16 [CM,256].
// ---------------------------------------------------------------------------
__global__ __launch_bounds__(256) void deform_attn_kernel(
    const short* __restrict__ v, const float* __restrict__ comb,
    short* __restrict__ outs)
{
    int g  = blockIdx.x * 16 + (threadIdx.x >> 4);
    int d2 = threadIdx.x & 15;
    int bn = g >> 3, h = g & 7;
    int n  = bn % NPix;
    int row = n / WW, col = n % WW;
    int base_v = (bn / NPix) * NPix;

    const float* cb = comb + (size_t)bn * 96;
    float l0 = cb[64 + h * 4 + 0], l1 = cb[64 + h * 4 + 1];
    float l2 = cb[64 + h * 4 + 2], l3 = cb[64 + h * 4 + 3];
    float mx = fmaxf(fmaxf(l0, l1), fmaxf(l2, l3));
    float e0 = __expf(l0 - mx), e1 = __expf(l1 - mx);
    float e2 = __expf(l2 - mx), e3 = __expf(l3 - mx);
    float inv = 1.0f / (e0 + e1 + e2 + e3);
    float aw[4] = {e0 * inv, e1 * inv, e2 * inv, e3 * inv};

    float acc0 = 0.0f, acc1 = 0.0f;
    size_t chb = (size_t)h * HD + d2 * 2;
    #pragma unroll
    for (int p = 0; p < 4; ++p) {
        float dx = cb[h * 8 + p * 2 + 0];
        float dy = cb[h * 8 + p * 2 + 1];
        float px = (float)col + dx;
        float py = (float)row + dy;
        float x0f = floorf(px), y0f = floorf(py);
        float wx = px - x0f, wy = py - y0f;
        int x0i = min(max((int)x0f, 0), WW - 1);
        int y0i = min(max((int)y0f, 0), HH - 1);
        int x1i = min(x0i + 1, WW - 1);
        int y1i = min(y0i + 1, HH - 1);
        unsigned u00 = *(const unsigned*)&v[(size_t)(base_v + y0i * WW + x0i) * Dm + chb];
        unsigned u01 = *(const unsigned*)&v[(size_t)(base_v + y0i * WW + x1i) * Dm + chb];
        unsigned u10 = *(const unsigned*)&v[(size_t)(base_v + y1i * WW + x0i) * Dm + chb];
        unsigned u11 = *(const unsigned*)&v[(size_t)(base_v + y1i * WW + x1i) * Dm + chb];
        float w00 = (1.0f - wx) * (1.0f - wy), w01 = wx * (1.0f - wy);
        float w10 = (1.0f - wx) * wy,          w11 = wx * wy;
        float s0 = bf2f((unsigned short)u00) * w00 + bf2f((unsigned short)u01) * w01
                 + bf2f((unsigned short)u10) * w10 + bf2f((unsigned short)u11) * w11;
        float s1 = bf2f((unsigned short)(u00 >> 16)) * w00 + bf2f((unsigned short)(u01 >> 16)) * w01
                 + bf2f((unsigned short)(u10 >> 16)) * w10 + bf2f((unsigned short)(u11 >> 16)) * w11;
        acc0 = fmaf(aw[p], s0, acc0);
        acc1 = fmaf(aw[p], s1, acc1);
    }
    unsigned outw = (unsigned)f2bf(acc0) | ((unsigned)f2bf(acc1) << 16);
    *(unsigned*)&outs[(size_t)bn * Dm + chb] = outw;
}

// ---------------------------------------------------------------------------
extern "C" void kernel_launch(void* const* d_in, const int* in_sizes, int n_in,
                              void* d_out, int out_size, void* d_ws, size_t ws_size,
                              hipStream_t stream)
{
    const float* src  = (const float*)d_in[0];
    const float* Wv   = (const float*)d_in[1];
    const float* bv   = (const float*)d_in[2];
    const float* Woff = (const float*)d_in[3];
    const float* boff = (const float*)d_in[4];
    const float* Wa   = (const float*)d_in[5];
    const float* ba   = (const float*)d_in[6];
    const float* Wo   = (const float*)d_in[7];
    const float* bo   = (const float*)d_in[8];
    const float* W1   = (const float*)d_in[9];
    const float* b1   = (const float*)d_in[10];
    const float* W2   = (const float*)d_in[11];
    const float* b2   = (const float*)d_in[12];
    const float* g1   = (const float*)d_in[13];
    const float* be1  = (const float*)d_in[14];
    const float* g2   = (const float*)d_in[15];
    const float* be2  = (const float*)d_in[16];

    float* x = (float*)d_out;   // fp32 master activations

    char* cur = (char*)d_ws;
    auto take = [&](size_t bytes) { char* p = cur; cur += (bytes + 255) & ~(size_t)255; return p; };
    short* WcatT = (short*)take((size_t)Lnum * 352 * Dm * 2);
    short* WoT   = (short*)take((size_t)Lnum * Dm * Dm * 2);
    short* W1T   = (short*)take((size_t)Lnum * Dm * FFd * 2);  // [l][1024][256]
    short* W2T   = (short*)take((size_t)Lnum * FFd * Dm * 2);  // [l][256][1024]
    float* bcat  = (float*)take((size_t)Lnum * 352 * 4);
    short* xb    = (short*)take((size_t)Mrows * Dm * 2);
    size_t fixedB = (size_t)(cur - (char*)d_ws);

    const size_t perRowB = 512 + 512 + 384 + 2048;   // v, sbuf, comb, h
    int k = 8;
    while (k > 1 && fixedB + (size_t)k * NPix * perRowB > ws_size) k >>= 1;
    if (fixedB + (size_t)k * NPix * perRowB > ws_size) return;
    const int CM = k * NPix;
    const int nChunks = Bq / k;

    short* v    = (short*)take((size_t)CM * Dm * 2);
    short* sbuf = (short*)take((size_t)CM * Dm * 2);
    float* comb = (float*)take((size_t)CM * 96 * 4);
    short* h    = (short*)take((size_t)CM * FFd * 2);

    repack_kernel<<<dim3(4, 4, Lnum),  256, 0, stream>>>(Wv,   WcatT, Dm,  Dm,  352 * Dm,   0);
    repack_kernel<<<dim3(1, 4, Lnum),  256, 0, stream>>>(Woff, WcatT, Dm,  64,  352 * Dm, 256);
    repack_kernel<<<dim3(1, 4, Lnum),  256, 0, stream>>>(Wa,   WcatT, Dm,  32,  352 * Dm, 320);
    repack_kernel<<<dim3(4, 4, Lnum),  256, 0, stream>>>(Wo,   WoT,   Dm,  Dm,  Dm * Dm,    0);
    repack_kernel<<<dim3(16, 4, Lnum), 256, 0, stream>>>(W1,   W1T,   Dm,  FFd, Dm * FFd,   0);
    repack_kernel<<<dim3(4, 16, Lnum), 256, 0, stream>>>(W2,   W2T,   FFd, Dm,  FFd * Dm,   0);
    bcat_kernel<<<Lnum, 352, 0, stream>>>(bv, boff, ba, bcat);

    pos_add_kernel<<<Mrows, 256, 0, stream>>>(src, x, xb);

    const int gy128 = (CM + 127) / 128;   // 625
    const int gLN   = (CM + 127) / 128;

    for (int l = 0; l < Lnum; ++l) {
        const short* WcatT_l = WcatT + (size_t)l * 352 * Dm;
        const short* WoT_l   = WoT   + (size_t)l * Dm * Dm;
        const short* W1T_l   = W1T   + (size_t)l * Dm * FFd;
        const short* W2T_l   = W2T   + (size_t)l * FFd * Dm;

        for (int c = 0; c < nChunks; ++c) {
            size_t rowOff = (size_t)c * CM;
            float* xc  = x  + rowOff * Dm;
            short* xbc = xb + rowOff * Dm;

            // v | comb = xb @ WcatT  (K=256)
            gemm_mfma_kernel<4, 2><<<dim3(3, gy128), 256, 0, stream>>>(
                xbc, WcatT_l, bcat + l * 352, v, comb, CM, 352, 0);
            // sbuf = deformable sampling (bf16)
            deform_attn_kernel<<<CM / 2, 256, 0, stream>>>(v, comb, sbuf);
            // x = LN(x + sbuf @ WoT + bo)  (K=256)
            gemm_ln_kernel<4><<<gLN, 512, 0, stream>>>(
                sbuf, WoT_l, bo + l * Dm, g1 + l * Dm, be1 + l * Dm, xc, xbc, CM);
            // h = gelu(xb @ W1T + b1)  (K=256, Nc=1024)
            gemm_mfma_kernel<4, 0><<<dim3(8, gy128), 256, 0, stream>>>(
                xbc, W1T_l, b1 + l * FFd, h, nullptr, CM, FFd, FFd);
            // x = LN(x + h @ W2T + b2)  (K=1024)
            gemm_ln_kernel<16><<<gLN, 512, 0, stream>>>(
                h, W2T_l, b2 + l * Dm, g2 + l * Dm, be2 + l * Dm, xc, xbc, CM);
        }
    }
}